// Round 17
// baseline (828.432 us; speedup 1.0000x reference)
//
#include <hip/hip_runtime.h>
#include <hip/hip_bf16.h>
#include <cstdint>
#include <cstddef>

#define T_TOK 8192
#define H_DIM 2048
#define I_DIM 1408
#define E_NUM 8
#define BM 128
#define BK 64
#define ROWS_CAP (2 * T_TOK + E_NUM * BM) /* 17408 */
#define MAX_MT (ROWS_CAP / BM)            /* 136 */
#define NT1 (I_DIM / 64)                  /* 22 */
#define NT2 (H_DIM / 128)                 /* 16 */

typedef __attribute__((ext_vector_type(8))) short short8;
typedef __attribute__((ext_vector_type(4))) float f32x4;
typedef __attribute__((ext_vector_type(2))) float f32x2;
typedef __attribute__((ext_vector_type(8))) unsigned short bf16x8;
typedef __attribute__((ext_vector_type(4))) unsigned short bf16x4;
typedef __attribute__((ext_vector_type(8))) _Float16 h16x8;

static __device__ __forceinline__ unsigned short f2bf(float f) {
  unsigned u = __float_as_uint(f);
  u += 0x7FFFu + ((u >> 16) & 1u);   // round-to-nearest-even
  return (unsigned short)(u >> 16);
}

static __device__ __forceinline__ void gld_lds16(const void* g, void* l) {
  __builtin_amdgcn_global_load_lds(
      (__attribute__((address_space(1))) unsigned int*)g,
      (__attribute__((address_space(3))) unsigned int*)l, 16, 0, 0);
}

// XCD-chunked bijective remap (nb % 8 == 0) + M-groups-of-G intra order.
template <int G>
static __device__ __forceinline__ void remap_tile(int bid, int nb, int nt_cols,
                                                  int& m_t, int& n_t) {
  int chunk = nb >> 3;
  int wg = (bid & 7) * chunk + (bid >> 3);
  int grp = wg / (nt_cols * G);
  int rem = wg % (nt_cols * G);
  n_t = rem / G;
  m_t = grp * G + rem % G;
}

// ---------------- router (fused x->bf16 convert) ---------------------------
__global__ __launch_bounds__(256) void router_kernel(
    const float* __restrict__ x, const float* __restrict__ rw,
    unsigned short* __restrict__ xb,
    int* __restrict__ topk_idx, float* __restrict__ topk_w, int* __restrict__ meta) {
  int t = blockIdx.x * 4 + (threadIdx.x >> 6);
  int lane = threadIdx.x & 63;
  const float* xr = x + (size_t)t * H_DIM;
  unsigned short* xbr = xb + (size_t)t * H_DIM;
  float acc[E_NUM];
#pragma unroll
  for (int e = 0; e < E_NUM; e++) acc[e] = 0.f;
  for (int j = lane * 4; j < H_DIM; j += 256) {
    f32x4 v = *(const f32x4*)(xr + j);
    bf16x4 b;
#pragma unroll
    for (int u = 0; u < 4; u++) b[u] = f2bf(v[u]);
    *(bf16x4*)(xbr + j) = b;
#pragma unroll
    for (int e = 0; e < E_NUM; e++) {
      f32x4 w = *(const f32x4*)(rw + e * H_DIM + j);
      acc[e] += v[0] * w[0] + v[1] * w[1] + v[2] * w[2] + v[3] * w[3];
    }
  }
#pragma unroll
  for (int e = 0; e < E_NUM; e++) {
    float v = acc[e];
#pragma unroll
    for (int s = 32; s > 0; s >>= 1) v += __shfl_xor(v, s);
    acc[e] = v;
  }
  if (lane == 0) {
    int i0 = 0;
#pragma unroll
    for (int e = 1; e < E_NUM; e++) if (acc[e] > acc[i0]) i0 = e;
    int i1 = (i0 == 0) ? 1 : 0;
#pragma unroll
    for (int e = 0; e < E_NUM; e++) if (e != i0 && acc[e] > acc[i1]) i1 = e;
    float mx = acc[0];
#pragma unroll
    for (int e = 1; e < E_NUM; e++) mx = fmaxf(mx, acc[e]);
    float sum = 0.f, p[E_NUM];
#pragma unroll
    for (int e = 0; e < E_NUM; e++) { p[e] = expf(acc[e] - mx); sum += p[e]; }
    float inv = 1.f / sum;
    topk_idx[t * 2] = i0;  topk_idx[t * 2 + 1] = i1;
    topk_w[t * 2] = p[i0] * inv;  topk_w[t * 2 + 1] = p[i1] * inv;
    atomicAdd(&meta[i0], 1);
    atomicAdd(&meta[i1], 1);
  }
}

// ---------------- scan -----------------------------------------------------
__global__ void scan_kernel(int* __restrict__ meta, int* __restrict__ row_token) {
  __shared__ int s_off[E_NUM + 1];
  if (threadIdx.x == 0) {
    int o = 0, nt = 0;
    for (int e = 0; e < E_NUM; e++) {
      meta[16 + e] = o; s_off[e] = o;
      int c = meta[e];
      int mtc = (c + BM - 1) / BM;
      for (int m = 0; m < mtc; m++) { meta[64 + nt] = e; meta[256 + nt] = o + m * BM; nt++; }
      o += mtc * BM;
      meta[8 + e] = 0; // cursor
    }
    meta[16 + E_NUM] = o; s_off[E_NUM] = o;
    meta[32] = nt;
  }
  __syncthreads();
  for (int e = 0; e < E_NUM; e++) {
    int lo = s_off[e] + meta[e], hi = s_off[e + 1];
    for (int r = lo + (int)threadIdx.x; r < hi; r += 64) row_token[r] = -1;
  }
}

// ---------------- bucket ---------------------------------------------------
__global__ __launch_bounds__(256) void bucket_kernel(
    const int* __restrict__ topk_idx, int* __restrict__ meta,
    int* __restrict__ row_token, int* __restrict__ tok2row) {
  int i = blockIdx.x * 256 + threadIdx.x;
  if (i >= 2 * T_TOK) return;
  int e = topk_idx[i];
  int pos = atomicAdd(&meta[8 + e], 1);
  int r = meta[16 + e] + pos;
  row_token[r] = i >> 1;
  tok2row[i] = r;
}

#define STAGE_A(buf, kof_)                                                    \
  {                                                                           \
    int kof = (kof_);                                                         \
    char* b = smem + (buf) * 32768;                                           \
    _Pragma("unroll") for (int i = 0; i < 4; i++)                             \
      gld_lds16(asrc[i] + kof, b + i * 4096 + wid * 1024);                    \
  }

// ---------------- GEMM1: h = silu(x@Wg)*(x@Wu) -----------------------------
// A: bf16 gld_lds (as before). B: fp32 from ORIGINAL wgu [H][2I] layout,
// reg-staged (issue-early/write-late, T14) with fused f32->bf16 convert and
// swizzled transpose ds_write_b128 -> the weight-transpose kernel is gone.
__global__ __launch_bounds__(256) void gemm1_kernel(
    const unsigned short* __restrict__ xb,   // [T][H] bf16
    const float* __restrict__ wgu,           // [E][H][2I] fp32 (ORIGINAL)
    unsigned short* __restrict__ hbuf,       // [ROWS_CAP][I] bf16
    const int* __restrict__ row_token, const int* __restrict__ meta) {
  int m_t, n_t;
  remap_tile<4>(blockIdx.x, NT1 * MAX_MT, NT1, m_t, n_t);
  if (m_t >= meta[32]) return;
  int e = meta[64 + m_t];
  int row0 = meta[256 + m_t];
  int n0h = n_t * 64;
  constexpr int CB = 2 * I_DIM;  // 2816, fp32 row stride of wgu

  __shared__ alignas(16) char smem[65536];  // 2 x (A 16K + B 16K)

  int tid = threadIdx.x, lane = tid & 63, wid = tid >> 6;
  const unsigned short* asrc[4];
  {
#pragma unroll
    for (int i = 0; i < 4; i++) {
      int r = i * 32 + (tid >> 3);
      int ch = ((tid & 7) ^ (r & 7)) * 8;
      int tok = row_token[row0 + r];
      if (tok < 0) tok = 0;
      asrc[i] = xb + (size_t)tok * H_DIM + ch;
    }
  }
  // B column pointers: thread owns n-pair (2n,2n+1) and two k-chunks.
  const float* bcol[2];
  int npair = tid & 63, kc0 = tid >> 6;
  {
    const float* wb = wgu + (size_t)e * H_DIM * CB;
    int n = npair * 2;
    int col = (n < 64) ? (n0h + n) : (I_DIM + n0h + (n - 64));
#pragma unroll
    for (int u = 0; u < 2; u++)
      bcol[u] = wb + (size_t)((kc0 + u * 4) * 8) * CB + col;
  }
  f32x2 rB[2][8];
  auto loadB = [&](int kof) {
#pragma unroll
    for (int u = 0; u < 2; u++)
#pragma unroll
      for (int j = 0; j < 8; j++)
        rB[u][j] = *(const f32x2*)(bcol[u] + (size_t)(kof + j) * CB);
  };
  auto writeB = [&](int buf) {
    unsigned short* sBw = (unsigned short*)(smem + buf * 32768 + 16384);
#pragma unroll
    for (int u = 0; u < 2; u++) {
      int kchunk = kc0 + u * 4;
#pragma unroll
      for (int o = 0; o < 2; o++) {
        int n = npair * 2 + o;
        bf16x8 v;
#pragma unroll
        for (int j = 0; j < 8; j++) v[j] = f2bf(rB[u][j][o]);
        *(bf16x8*)(sBw + n * 64 + ((kchunk ^ (n & 7)) << 3)) = v;
      }
    }
  };

  f32x4 acc[4][4] = {};
  int mrow = (wid >> 1) * 64 + (lane & 15);
  int brow = (wid & 1) * 64 + (lane & 15);

  constexpr int NK = H_DIM / BK;  // 32
  // prologue: tiles 0,1
  loadB(0);
  STAGE_A(0, 0);
  asm volatile("s_waitcnt vmcnt(0)" ::: "memory");
  writeB(0);
  loadB(BK);
  STAGE_A(1, BK);
  asm volatile("s_waitcnt vmcnt(0)" ::: "memory");
  writeB(1);
  asm volatile("s_waitcnt lgkmcnt(0)" ::: "memory");
  __builtin_amdgcn_s_barrier();
  int cur = 0;
  for (int kt = 0; kt < NK; kt++) {
    if (kt + 2 < NK) {
      loadB((kt + 2) * BK);                    // issue early (hides under MFMA)
      __builtin_amdgcn_sched_barrier(0);       // pin issue point
    }
    const unsigned short* sA = (const unsigned short*)(smem + cur * 32768);
    const unsigned short* sB = sA + 8192;
#pragma unroll
    for (int kk = 0; kk < 2; kk++) {
      int krd = ((kk * 4 + (lane >> 4)) ^ (lane & 7)) * 8;
      short8 af[4], bf[4];
#pragma unroll
      for (int f = 0; f < 4; f++) {
        af[f] = *(const short8*)(sA + (mrow + f * 16) * BK + krd);
        bf[f] = *(const short8*)(sB + (brow + f * 16) * BK + krd);
      }
#pragma unroll
      for (int fm = 0; fm < 4; fm++)
#pragma unroll
        for (int fn = 0; fn < 4; fn++)
          acc[fm][fn] = __builtin_amdgcn_mfma_f32_16x16x32_bf16(af[fm], bf[fn], acc[fm][fn], 0, 0, 0);
    }
    asm volatile("" ::: "memory");
    __builtin_amdgcn_s_barrier();              // WAR: all waves done with cur
    asm volatile("s_waitcnt vmcnt(0)" ::: "memory");
    if (kt + 2 < NK) {
      writeB(cur);                             // B tile kt+2 -> freed buffer
      STAGE_A(cur, (kt + 2) * BK);             // A tile kt+2 (async)
    }
    asm volatile("s_waitcnt lgkmcnt(0)" ::: "memory");
    __builtin_amdgcn_s_barrier();              // ready
    cur ^= 1;
  }

  // SwiGLU epilogue (known-good): odd waves publish U via LDS, even combine.
  float* xw = (float*)smem + (wid >> 1) * 4096;
  if (wid & 1) {
#pragma unroll
    for (int fm = 0; fm < 4; fm++)
#pragma unroll
      for (int r = 0; r < 4; r++) {
        int mloc = fm * 16 + (lane >> 4) * 4 + r;
#pragma unroll
        for (int fn = 0; fn < 4; fn++)
          xw[mloc * 64 + fn * 16 + (lane & 15)] = acc[fm][fn][r];
      }
  }
  __syncthreads();
  if (!(wid & 1)) {
    int mbase = row0 + (wid >> 1) * 64;
#pragma unroll
    for (int fm = 0; fm < 4; fm++)
#pragma unroll
      for (int r = 0; r < 4; r++) {
        int mloc = fm * 16 + (lane >> 4) * 4 + r;
        size_t rbase = (size_t)(mbase + mloc) * I_DIM + n0h;
#pragma unroll
        for (int fn = 0; fn < 4; fn++) {
          float g = acc[fm][fn][r];
          float u = xw[mloc * 64 + fn * 16 + (lane & 15)];
          float hv = (g / (1.f + __expf(-g))) * u;
          hbuf[rbase + fn * 16 + (lane & 15)] = f2bf(hv);
        }
      }
  }
}

// ---------------- GEMM2: part[row] = h @ Wd (f16, un-gated) ----------------
// A: bf16 hbuf gld_lds. B: fp32 from ORIGINAL wdn [I][H] layout, same
// reg-staged convert+transpose as gemm1.
__global__ __launch_bounds__(256) void gemm2_kernel(
    const unsigned short* __restrict__ hbuf, // [ROWS_CAP][I] bf16
    const float* __restrict__ wdn,           // [E][I][H] fp32 (ORIGINAL)
    _Float16* __restrict__ part,             // [ROWS_CAP][H] f16
    const int* __restrict__ meta) {
  int m_t, n_t;
  remap_tile<8>(blockIdx.x, NT2 * MAX_MT, NT2, m_t, n_t);
  if (m_t >= meta[32]) return;
  int e = meta[64 + m_t];
  int row0 = meta[256 + m_t];
  int n0 = n_t * 128;
  constexpr int CB = H_DIM;  // 2048, fp32 row stride of wdn

  __shared__ alignas(16) char smem[65536];

  int tid = threadIdx.x, lane = tid & 63, wid = tid >> 6;
  const unsigned short* asrc[4];
  {
#pragma unroll
    for (int i = 0; i < 4; i++) {
      int r = i * 32 + (tid >> 3);
      int ch = ((tid & 7) ^ (r & 7)) * 8;
      asrc[i] = hbuf + (size_t)(row0 + r) * I_DIM + ch;
    }
  }
  const float* bcol[2];
  int npair = tid & 63, kc0 = tid >> 6;
  {
    const float* wb = wdn + (size_t)e * I_DIM * CB;
    int col = n0 + npair * 2;
#pragma unroll
    for (int u = 0; u < 2; u++)
      bcol[u] = wb + (size_t)((kc0 + u * 4) * 8) * CB + col;
  }
  f32x2 rB[2][8];
  auto loadB = [&](int kof) {
#pragma unroll
    for (int u = 0; u < 2; u++)
#pragma unroll
      for (int j = 0; j < 8; j++)
        rB[u][j] = *(const f32x2*)(bcol[u] + (size_t)(kof + j) * CB);
  };
  auto writeB = [&](int buf) {
    unsigned short* sBw = (unsigned short*)(smem + buf * 32768 + 16384);
#pragma unroll
    for (int u = 0; u < 2; u++) {
      int kchunk = kc0 + u * 4;
#pragma unroll
      for (int o = 0; o < 2; o++) {
        int n = npair * 2 + o;
        bf16x8 v;
#pragma unroll
        for (int j = 0; j < 8; j++) v[j] = f2bf(rB[u][j][o]);
        *(bf16x8*)(sBw + n * 64 + ((kchunk ^ (n & 7)) << 3)) = v;
      }
    }
  };

  f32x4 acc[4][4] = {};
  int mrow = (wid >> 1) * 64 + (lane & 15);
  int brow = (wid & 1) * 64 + (lane & 15);

  constexpr int NK = I_DIM / BK;  // 22
  loadB(0);
  STAGE_A(0, 0);
  asm volatile("s_waitcnt vmcnt(0)" ::: "memory");
  writeB(0);
  loadB(BK);
  STAGE_A(1, BK);
  asm volatile("s_waitcnt vmcnt(0)" ::: "memory");
  writeB(1);
  asm volatile("s_waitcnt lgkmcnt(0)" ::: "memory");
  __builtin_amdgcn_s_barrier();
  int cur = 0;
  for (int kt = 0; kt < NK; kt++) {
    if (kt + 2 < NK) {
      loadB((kt + 2) * BK);
      __builtin_amdgcn_sched_barrier(0);
    }
    const unsigned short* sA = (const unsigned short*)(smem + cur * 32768);
    const unsigned short* sB = sA + 8192;
#pragma unroll
    for (int kk = 0; kk < 2; kk++) {
      int krd = ((kk * 4 + (lane >> 4)) ^ (lane & 7)) * 8;
      short8 af[4], bf[4];
#pragma unroll
      for (int f = 0; f < 4; f++) {
        af[f] = *(const short8*)(sA + (mrow + f * 16) * BK + krd);
        bf[f] = *(const short8*)(sB + (brow + f * 16) * BK + krd);
      }
#pragma unroll
      for (int fm = 0; fm < 4; fm++)
#pragma unroll
        for (int fn = 0; fn < 4; fn++)
          acc[fm][fn] = __builtin_amdgcn_mfma_f32_16x16x32_bf16(af[fm], bf[fn], acc[fm][fn], 0, 0, 0);
    }
    asm volatile("" ::: "memory");
    __builtin_amdgcn_s_barrier();
    asm volatile("s_waitcnt vmcnt(0)" ::: "memory");
    if (kt + 2 < NK) {
      writeB(cur);
      STAGE_A(cur, (kt + 2) * BK);
    }
    asm volatile("s_waitcnt lgkmcnt(0)" ::: "memory");
    __builtin_amdgcn_s_barrier();
    cur ^= 1;
  }
  // epilogue: f16 restage into chunk-XOR-swizzled per-wave [64][64] tile,
  // then b128 coalesced stores (all waves past final barrier).
  _Float16* stg = (_Float16*)(smem + wid * 8192);
  int l15 = lane & 15;
#pragma unroll
  for (int fm = 0; fm < 4; fm++)
#pragma unroll
    for (int r = 0; r < 4; r++) {
      int mloc = fm * 16 + (lane >> 4) * 4 + r;
#pragma unroll
      for (int fn = 0; fn < 4; fn++) {
        int nl = fn * 16 + l15;
        stg[mloc * 64 + (((nl >> 3) ^ (mloc & 7)) << 3) + (nl & 7)] =
            (_Float16)acc[fm][fn][r];
      }
    }
  int m0 = (wid >> 1) * 64;
  int nbase = n0 + (wid & 1) * 64;
  int ca = lane & 7;
#pragma unroll
  for (int it = 0; it < 8; it++) {
    int mr = it * 8 + (lane >> 3);
    h16x8 v = *(const h16x8*)(stg + mr * 64 + ((ca ^ (mr & 7)) << 3));
    *(h16x8*)(part + (size_t)(row0 + m0 + mr) * H_DIM + nbase + ca * 8) = v;
  }
}

// ---------------- combine: out[t] = w0*part[r0] + w1*part[r1] --------------
__global__ __launch_bounds__(256) void combine_kernel(
    const _Float16* __restrict__ part, const int* __restrict__ tok2row,
    const float* __restrict__ topk_w, float* __restrict__ out) {
  int t = blockIdx.x;
  int c = threadIdx.x * 8;
  int r0 = tok2row[2 * t], r1 = tok2row[2 * t + 1];
  float w0 = topk_w[2 * t], w1 = topk_w[2 * t + 1];
  h16x8 p0 = *(const h16x8*)(part + (size_t)r0 * H_DIM + c);
  h16x8 p1 = *(const h16x8*)(part + (size_t)r1 * H_DIM + c);
  float* o = out + (size_t)t * H_DIM + c;
  f32x4 lo, hi;
#pragma unroll
  for (int j = 0; j < 4; j++) lo[j] = w0 * (float)p0[j] + w1 * (float)p1[j];
#pragma unroll
  for (int j = 0; j < 4; j++) hi[j] = w0 * (float)p0[4 + j] + w1 * (float)p1[4 + j];
  *(f32x4*)o = lo;
  *(f32x4*)(o + 4) = hi;
}

extern "C" void kernel_launch(void* const* d_in, const int* in_sizes, int n_in,
                              void* d_out, int out_size, void* d_ws, size_t ws_size,
                              hipStream_t stream) {
  const float* x   = (const float*)d_in[0];
  const float* rw  = (const float*)d_in[1];
  const float* wgu = (const float*)d_in[2];
  const float* wdn = (const float*)d_in[3];
  float* out = (float*)d_out;

  char* ws = (char*)d_ws;
  size_t off = 0;
  auto alloc = [&](size_t bytes) {
    void* p = ws + off;
    off += (bytes + 255) & ~(size_t)255;
    return p;
  };
  int* meta            = (int*)alloc(4096);
  int* topk_idx        = (int*)alloc((size_t)2 * T_TOK * 4);
  float* topk_w        = (float*)alloc((size_t)2 * T_TOK * 4);
  int* tok2row         = (int*)alloc((size_t)2 * T_TOK * 4);
  int* row_token       = (int*)alloc((size_t)ROWS_CAP * 4);
  unsigned short* xb    = (unsigned short*)alloc((size_t)T_TOK * H_DIM * 2);
  unsigned short* hbuf  = (unsigned short*)alloc((size_t)ROWS_CAP * I_DIM * 2);
  _Float16* part        = (_Float16*)alloc((size_t)ROWS_CAP * H_DIM * 2);

  if (off > ws_size) { // workspace too small: fail loudly (zero output)
    (void)hipMemsetAsync(d_out, 0, (size_t)out_size * sizeof(float), stream);
    return;
  }

  (void)hipMemsetAsync(meta, 0, 4096, stream);

  // routing (x->bf16 fused); weight conversion now fused into GEMM staging
  router_kernel<<<T_TOK / 4, 256, 0, stream>>>(x, rw, xb, topk_idx, topk_w, meta);
  scan_kernel<<<1, 64, 0, stream>>>(meta, row_token);
  bucket_kernel<<<(2 * T_TOK + 255) / 256, 256, 0, stream>>>(topk_idx, meta, row_token, tok2row);

  // grouped expert MLP (B operands read original fp32 weights directly)
  gemm1_kernel<<<NT1 * MAX_MT, 256, 0, stream>>>(xb, wgu, hbuf, row_token, meta);
  gemm2_kernel<<<NT2 * MAX_MT, 256, 0, stream>>>(hbuf, wdn, part, meta);
  combine_kernel<<<T_TOK, 256, 0, stream>>>(part, tok2row, topk_w, out);
}

// Round 18
// 718.147 us; speedup vs baseline: 1.1536x; 1.1536x over previous
//
#include <hip/hip_runtime.h>
#include <hip/hip_bf16.h>
#include <cstdint>
#include <cstddef>

#define T_TOK 8192
#define H_DIM 2048
#define I_DIM 1408
#define E_NUM 8
#define BM 128
#define BK 64
#define ROWS_CAP (2 * T_TOK + E_NUM * BM) /* 17408 */
#define MAX_MT (ROWS_CAP / BM)            /* 136 */
#define NT1 (I_DIM / 64)                  /* 22 */
#define NT2 (H_DIM / 128)                 /* 16 */

typedef __attribute__((ext_vector_type(8))) short short8;
typedef __attribute__((ext_vector_type(4))) float f32x4;
typedef __attribute__((ext_vector_type(8))) unsigned short bf16x8;
typedef __attribute__((ext_vector_type(4))) unsigned short bf16x4;
typedef __attribute__((ext_vector_type(8))) _Float16 h16x8;

static __device__ __forceinline__ unsigned short f2bf(float f) {
  unsigned u = __float_as_uint(f);
  u += 0x7FFFu + ((u >> 16) & 1u);   // round-to-nearest-even
  return (unsigned short)(u >> 16);
}

static __device__ __forceinline__ void gld_lds16(const void* g, void* l) {
  __builtin_amdgcn_global_load_lds(
      (__attribute__((address_space(1))) unsigned int*)g,
      (__attribute__((address_space(3))) unsigned int*)l, 16, 0, 0);
}

// XCD-chunked bijective remap (nb % 8 == 0) + M-groups-of-G intra order.
template <int G>
static __device__ __forceinline__ void remap_tile(int bid, int nb, int nt_cols,
                                                  int& m_t, int& n_t) {
  int chunk = nb >> 3;
  int wg = (bid & 7) * chunk + (bid >> 3);
  int grp = wg / (nt_cols * G);
  int rem = wg % (nt_cols * G);
  n_t = rem / G;
  m_t = grp * G + rem % G;
}

// ---------------- router (fused x->bf16 convert) ---------------------------
__global__ __launch_bounds__(256) void router_kernel(
    const float* __restrict__ x, const float* __restrict__ rw,
    unsigned short* __restrict__ xb,
    int* __restrict__ topk_idx, float* __restrict__ topk_w, int* __restrict__ meta) {
  int t = blockIdx.x * 4 + (threadIdx.x >> 6);
  int lane = threadIdx.x & 63;
  const float* xr = x + (size_t)t * H_DIM;
  unsigned short* xbr = xb + (size_t)t * H_DIM;
  float acc[E_NUM];
#pragma unroll
  for (int e = 0; e < E_NUM; e++) acc[e] = 0.f;
  for (int j = lane * 4; j < H_DIM; j += 256) {
    f32x4 v = *(const f32x4*)(xr + j);
    bf16x4 b;
#pragma unroll
    for (int u = 0; u < 4; u++) b[u] = f2bf(v[u]);
    *(bf16x4*)(xbr + j) = b;
#pragma unroll
    for (int e = 0; e < E_NUM; e++) {
      f32x4 w = *(const f32x4*)(rw + e * H_DIM + j);
      acc[e] += v[0] * w[0] + v[1] * w[1] + v[2] * w[2] + v[3] * w[3];
    }
  }
#pragma unroll
  for (int e = 0; e < E_NUM; e++) {
    float v = acc[e];
#pragma unroll
    for (int s = 32; s > 0; s >>= 1) v += __shfl_xor(v, s);
    acc[e] = v;
  }
  if (lane == 0) {
    int i0 = 0;
#pragma unroll
    for (int e = 1; e < E_NUM; e++) if (acc[e] > acc[i0]) i0 = e;
    int i1 = (i0 == 0) ? 1 : 0;
#pragma unroll
    for (int e = 0; e < E_NUM; e++) if (e != i0 && acc[e] > acc[i1]) i1 = e;
    float mx = acc[0];
#pragma unroll
    for (int e = 1; e < E_NUM; e++) mx = fmaxf(mx, acc[e]);
    float sum = 0.f, p[E_NUM];
#pragma unroll
    for (int e = 0; e < E_NUM; e++) { p[e] = expf(acc[e] - mx); sum += p[e]; }
    float inv = 1.f / sum;
    topk_idx[t * 2] = i0;  topk_idx[t * 2 + 1] = i1;
    topk_w[t * 2] = p[i0] * inv;  topk_w[t * 2 + 1] = p[i1] * inv;
    atomicAdd(&meta[i0], 1);
    atomicAdd(&meta[i1], 1);
  }
}

// ---------------- scan -----------------------------------------------------
__global__ void scan_kernel(int* __restrict__ meta, int* __restrict__ row_token) {
  __shared__ int s_off[E_NUM + 1];
  if (threadIdx.x == 0) {
    int o = 0, nt = 0;
    for (int e = 0; e < E_NUM; e++) {
      meta[16 + e] = o; s_off[e] = o;
      int c = meta[e];
      int mtc = (c + BM - 1) / BM;
      for (int m = 0; m < mtc; m++) { meta[64 + nt] = e; meta[256 + nt] = o + m * BM; nt++; }
      o += mtc * BM;
      meta[8 + e] = 0; // cursor
    }
    meta[16 + E_NUM] = o; s_off[E_NUM] = o;
    meta[32] = nt;
  }
  __syncthreads();
  for (int e = 0; e < E_NUM; e++) {
    int lo = s_off[e] + meta[e], hi = s_off[e + 1];
    for (int r = lo + (int)threadIdx.x; r < hi; r += 64) row_token[r] = -1;
  }
}

// ---------------- bucket ---------------------------------------------------
__global__ __launch_bounds__(256) void bucket_kernel(
    const int* __restrict__ topk_idx, int* __restrict__ meta,
    int* __restrict__ row_token, int* __restrict__ tok2row) {
  int i = blockIdx.x * 256 + threadIdx.x;
  if (i >= 2 * T_TOK) return;
  int e = topk_idx[i];
  int pos = atomicAdd(&meta[8 + e], 1);
  int r = meta[16 + e] + pos;
  row_token[r] = i >> 1;
  tok2row[i] = r;
}

// ---------------- transpose+convert via async gld_lds staging --------------
// [R][C] fp32 -> [C][R] bf16, 128x128 tiles. Phase A: 16 gld_lds/thread
// stage the fp32 tile with PRE-SWIZZLED global source (LDS 16B-chunk pc of
// row r holds logical chunk pc ^ key(r), key(r)=(r&7)^((r>>3)&7)); linear
// LDS dest (m104-safe). Phase B: transposed f32 reads are 2-way (free),
// f2bf, b128 coalesced global stores.
__global__ __launch_bounds__(256) void tcvt2_kernel(
    const float* __restrict__ wgu, const float* __restrict__ wdn,
    unsigned short* __restrict__ wgu_t, unsigned short* __restrict__ wd_t) {
  __shared__ alignas(16) float st[128 * 128];  // 64 KB
  int z = blockIdx.z;
  const float* src; unsigned short* dst; int R, C;
  if (z < E_NUM) {
    R = H_DIM; C = 2 * I_DIM;
    src = wgu + (size_t)z * R * C;  dst = wgu_t + (size_t)z * R * C;
  } else {
    R = I_DIM; C = H_DIM;
    src = wdn + (size_t)(z - E_NUM) * R * C;  dst = wd_t + (size_t)(z - E_NUM) * R * C;
  }
  int c0 = blockIdx.x * 128, r0 = blockIdx.y * 128;
  if (c0 >= C || r0 >= R) return;
  int tid = threadIdx.x, l = tid & 63, w = tid >> 6;
#pragma unroll
  for (int i = 0; i < 16; i++) {
    int r = i * 8 + w * 2 + (l >> 5);
    int key = (r & 7) ^ ((r >> 3) & 7);
    int c4 = (l & 31) ^ key;
    gld_lds16(src + (size_t)(r0 + r) * C + c0 + c4 * 4,
              (char*)st + (i * 8 + w * 2) * 512);
  }
  __syncthreads();  // vmcnt(0) drain + barrier
  int ca = tid & 15, cg = tid >> 4;
#pragma unroll
  for (int it = 0; it < 8; it++) {
    int c = it * 16 + cg;
    bf16x8 o;
#pragma unroll
    for (int j = 0; j < 8; j++) {
      int r = ca * 8 + j;
      int key = (r & 7) ^ ((r >> 3) & 7);
      o[j] = f2bf(st[r * 128 + (((c >> 2) ^ key) << 2) + (c & 3)]);
    }
    *(bf16x8*)(dst + (size_t)(c0 + c) * R + r0 + ca * 8) = o;
  }
}

// ---------------- GEMM1: h = silu(x@Wg)*(x@Wu) -----------------------------
// Counted-vmcnt pipeline (T4): 2 buffers, prefetch distance 2, raw barriers,
// never drain vmcnt to 0 in steady state.
__global__ __launch_bounds__(256) void gemm1_kernel(
    const unsigned short* __restrict__ xb,   // [T][H] bf16
    const unsigned short* __restrict__ wgu,  // [E][2I][H] bf16 (transposed)
    unsigned short* __restrict__ hbuf,       // [ROWS_CAP][I] bf16
    const int* __restrict__ row_token, const int* __restrict__ meta) {
  int m_t, n_t;
  remap_tile<4>(blockIdx.x, NT1 * MAX_MT, NT1, m_t, n_t);
  if (m_t >= meta[32]) return;
  int e = meta[64 + m_t];
  int row0 = meta[256 + m_t];
  int n0h = n_t * 64;

  __shared__ alignas(16) char smem[65536];  // 2 x (A 16K + B 16K)

  int tid = threadIdx.x, lane = tid & 63, wid = tid >> 6;
  const unsigned short* asrc[4];
  const unsigned short* bsrc[4];
  {
    const unsigned short* wb = wgu + (size_t)e * (2 * (size_t)I_DIM) * H_DIM;
#pragma unroll
    for (int i = 0; i < 4; i++) {
      int r = i * 32 + (tid >> 3);
      int ch = ((tid & 7) ^ (r & 7)) * 8;  // inverse-swizzled source chunk
      int tok = row_token[row0 + r];
      if (tok < 0) tok = 0;
      asrc[i] = xb + (size_t)tok * H_DIM + ch;
      int wr = (r < 64) ? (n0h + r) : (I_DIM + n0h + (r - 64));
      bsrc[i] = wb + (size_t)wr * H_DIM + ch;
    }
  }
  f32x4 acc[4][4] = {};
  int mrow = (wid >> 1) * 64 + (lane & 15);
  int brow = (wid & 1) * 64 + (lane & 15);

#define STAGE1(buf, kof_)                                                     \
  {                                                                           \
    int kof = (kof_);                                                         \
    char* b = smem + (buf) * 32768;                                           \
    _Pragma("unroll") for (int i = 0; i < 4; i++) {                           \
      gld_lds16(asrc[i] + kof, b + i * 4096 + wid * 1024);                    \
      gld_lds16(bsrc[i] + kof, b + 16384 + i * 4096 + wid * 1024);            \
    }                                                                         \
  }

  constexpr int NK1 = H_DIM / BK;  // 32
  STAGE1(0, 0);
  STAGE1(1, BK);
  for (int kt = 0; kt < NK1; kt++) {
    int cur = kt & 1;
    // wait my 8 loads for cur (leave the next tile's 8 in flight)
    if (kt + 1 < NK1) { asm volatile("s_waitcnt vmcnt(8)" ::: "memory"); }
    else              { asm volatile("s_waitcnt vmcnt(0)" ::: "memory"); }
    __builtin_amdgcn_s_barrier();   // all waves' loads for cur are in LDS
    const unsigned short* sA = (const unsigned short*)(smem + cur * 32768);
    const unsigned short* sB = sA + 8192;
#pragma unroll
    for (int kk = 0; kk < 2; kk++) {
      int krd = ((kk * 4 + (lane >> 4)) ^ (lane & 7)) * 8;
      short8 af[4], bf[4];
#pragma unroll
      for (int f = 0; f < 4; f++) {
        af[f] = *(const short8*)(sA + (mrow + f * 16) * BK + krd);
        bf[f] = *(const short8*)(sB + (brow + f * 16) * BK + krd);
      }
#pragma unroll
      for (int fm = 0; fm < 4; fm++)
#pragma unroll
        for (int fn = 0; fn < 4; fn++)
          acc[fm][fn] = __builtin_amdgcn_mfma_f32_16x16x32_bf16(af[fm], bf[fn], acc[fm][fn], 0, 0, 0);
    }
    asm volatile("" ::: "memory");
    __builtin_amdgcn_s_barrier();   // all waves done reading cur (WAR fence)
    asm volatile("" ::: "memory");
    if (kt + 2 < NK1) STAGE1(cur, (kt + 2) * BK);
  }

  // SwiGLU epilogue (known-good): odd waves publish U via LDS, even combine.
  float* xw = (float*)smem + (wid >> 1) * 4096;  // 64x64 f32 per wave-pair
  if (wid & 1) {
#pragma unroll
    for (int fm = 0; fm < 4; fm++)
#pragma unroll
      for (int r = 0; r < 4; r++) {
        int mloc = fm * 16 + (lane >> 4) * 4 + r;
#pragma unroll
        for (int fn = 0; fn < 4; fn++)
          xw[mloc * 64 + fn * 16 + (lane & 15)] = acc[fm][fn][r];
      }
  }
  __syncthreads();
  if (!(wid & 1)) {
    int mbase = row0 + (wid >> 1) * 64;
#pragma unroll
    for (int fm = 0; fm < 4; fm++)
#pragma unroll
      for (int r = 0; r < 4; r++) {
        int mloc = fm * 16 + (lane >> 4) * 4 + r;
        size_t rbase = (size_t)(mbase + mloc) * I_DIM + n0h;
#pragma unroll
        for (int fn = 0; fn < 4; fn++) {
          float g = acc[fm][fn][r];
          float u = xw[mloc * 64 + fn * 16 + (lane & 15)];
          float hv = (g / (1.f + __expf(-g))) * u;
          hbuf[rbase + fn * 16 + (lane & 15)] = f2bf(hv);
        }
      }
  }
}

// ---------------- GEMM2: part[row] = h @ Wd (f16, un-gated) ----------------
__global__ __launch_bounds__(256) void gemm2_kernel(
    const unsigned short* __restrict__ hbuf, // [ROWS_CAP][I] bf16
    const unsigned short* __restrict__ wd,   // [E][H][I] bf16 (transposed)
    _Float16* __restrict__ part,             // [ROWS_CAP][H] f16
    const int* __restrict__ meta) {
  int m_t, n_t;
  remap_tile<8>(blockIdx.x, NT2 * MAX_MT, NT2, m_t, n_t);
  if (m_t >= meta[32]) return;
  int e = meta[64 + m_t];
  int row0 = meta[256 + m_t];
  int n0 = n_t * 128;

  __shared__ alignas(16) char smem[65536];

  int tid = threadIdx.x, lane = tid & 63, wid = tid >> 6;
  const unsigned short* asrc[4];
  const unsigned short* bsrc[4];
  {
    const unsigned short* wb = wd + (size_t)e * (size_t)H_DIM * I_DIM;
#pragma unroll
    for (int i = 0; i < 4; i++) {
      int r = i * 32 + (tid >> 3);
      int ch = ((tid & 7) ^ (r & 7)) * 8;
      asrc[i] = hbuf + (size_t)(row0 + r) * I_DIM + ch;
      bsrc[i] = wb + (size_t)(n0 + r) * I_DIM + ch;
    }
  }
  f32x4 acc[4][4] = {};
  int mrow = (wid >> 1) * 64 + (lane & 15);
  int brow = (wid & 1) * 64 + (lane & 15);

  constexpr int NK2 = I_DIM / BK;  // 22
  STAGE1(0, 0);
  STAGE1(1, BK);
  for (int kt = 0; kt < NK2; kt++) {
    int cur = kt & 1;
    if (kt + 1 < NK2) { asm volatile("s_waitcnt vmcnt(8)" ::: "memory"); }
    else              { asm volatile("s_waitcnt vmcnt(0)" ::: "memory"); }
    __builtin_amdgcn_s_barrier();
    const unsigned short* sA = (const unsigned short*)(smem + cur * 32768);
    const unsigned short* sB = sA + 8192;
#pragma unroll
    for (int kk = 0; kk < 2; kk++) {
      int krd = ((kk * 4 + (lane >> 4)) ^ (lane & 7)) * 8;
      short8 af[4], bf[4];
#pragma unroll
      for (int f = 0; f < 4; f++) {
        af[f] = *(const short8*)(sA + (mrow + f * 16) * BK + krd);
        bf[f] = *(const short8*)(sB + (brow + f * 16) * BK + krd);
      }
#pragma unroll
      for (int fm = 0; fm < 4; fm++)
#pragma unroll
        for (int fn = 0; fn < 4; fn++)
          acc[fm][fn] = __builtin_amdgcn_mfma_f32_16x16x32_bf16(af[fm], bf[fn], acc[fm][fn], 0, 0, 0);
    }
    asm volatile("" ::: "memory");
    __builtin_amdgcn_s_barrier();
    asm volatile("" ::: "memory");
    if (kt + 2 < NK2) STAGE1(cur, (kt + 2) * BK);
  }
  // epilogue: f16 restage into chunk-XOR-swizzled per-wave [64][64] tile,
  // then b128 coalesced stores (all waves past final barrier).
  _Float16* stg = (_Float16*)(smem + wid * 8192);
  int l15 = lane & 15;
#pragma unroll
  for (int fm = 0; fm < 4; fm++)
#pragma unroll
    for (int r = 0; r < 4; r++) {
      int mloc = fm * 16 + (lane >> 4) * 4 + r;
#pragma unroll
      for (int fn = 0; fn < 4; fn++) {
        int nl = fn * 16 + l15;
        stg[mloc * 64 + (((nl >> 3) ^ (mloc & 7)) << 3) + (nl & 7)] =
            (_Float16)acc[fm][fn][r];
      }
    }
  int m0 = (wid >> 1) * 64;
  int nbase = n0 + (wid & 1) * 64;
  int ca = lane & 7;
#pragma unroll
  for (int it = 0; it < 8; it++) {
    int mr = it * 8 + (lane >> 3);
    h16x8 v = *(const h16x8*)(stg + mr * 64 + ((ca ^ (mr & 7)) << 3));
    *(h16x8*)(part + (size_t)(row0 + m0 + mr) * H_DIM + nbase + ca * 8) = v;
  }
}

// ---------------- combine: out[t] = w0*part[r0] + w1*part[r1] --------------
__global__ __launch_bounds__(256) void combine_kernel(
    const _Float16* __restrict__ part, const int* __restrict__ tok2row,
    const float* __restrict__ topk_w, float* __restrict__ out) {
  int t = blockIdx.x;
  int c = threadIdx.x * 8;
  int r0 = tok2row[2 * t], r1 = tok2row[2 * t + 1];
  float w0 = topk_w[2 * t], w1 = topk_w[2 * t + 1];
  h16x8 p0 = *(const h16x8*)(part + (size_t)r0 * H_DIM + c);
  h16x8 p1 = *(const h16x8*)(part + (size_t)r1 * H_DIM + c);
  float* o = out + (size_t)t * H_DIM + c;
  f32x4 lo, hi;
#pragma unroll
  for (int j = 0; j < 4; j++) lo[j] = w0 * (float)p0[j] + w1 * (float)p1[j];
#pragma unroll
  for (int j = 0; j < 4; j++) hi[j] = w0 * (float)p0[4 + j] + w1 * (float)p1[4 + j];
  *(f32x4*)o = lo;
  *(f32x4*)(o + 4) = hi;
}

extern "C" void kernel_launch(void* const* d_in, const int* in_sizes, int n_in,
                              void* d_out, int out_size, void* d_ws, size_t ws_size,
                              hipStream_t stream) {
  const float* x   = (const float*)d_in[0];
  const float* rw  = (const float*)d_in[1];
  const float* wgu = (const float*)d_in[2];
  const float* wdn = (const float*)d_in[3];
  float* out = (float*)d_out;

  char* ws = (char*)d_ws;
  size_t off = 0;
  auto alloc = [&](size_t bytes) {
    void* p = ws + off;
    off += (bytes + 255) & ~(size_t)255;
    return p;
  };
  int* meta            = (int*)alloc(4096);
  int* topk_idx        = (int*)alloc((size_t)2 * T_TOK * 4);
  float* topk_w        = (float*)alloc((size_t)2 * T_TOK * 4);
  int* tok2row         = (int*)alloc((size_t)2 * T_TOK * 4);
  int* row_token       = (int*)alloc((size_t)ROWS_CAP * 4);
  unsigned short* xb    = (unsigned short*)alloc((size_t)T_TOK * H_DIM * 2);
  unsigned short* wgu_t = (unsigned short*)alloc((size_t)E_NUM * 2 * I_DIM * H_DIM * 2);
  unsigned short* wd_t  = (unsigned short*)alloc((size_t)E_NUM * H_DIM * I_DIM * 2);
  unsigned short* hbuf  = (unsigned short*)alloc((size_t)ROWS_CAP * I_DIM * 2);
  // part[ROWS_CAP][H] f16 (71.3 MB) aliases wgu_t (92.3 MB; dead after gemm1)
  _Float16* part = (_Float16*)wgu_t;

  if (off > ws_size) { // workspace too small: fail loudly (zero output)
    (void)hipMemsetAsync(d_out, 0, (size_t)out_size * sizeof(float), stream);
    return;
  }

  (void)hipMemsetAsync(meta, 0, 4096, stream);

  // weight transpose+convert (async gld_lds staging) and routing
  tcvt2_kernel<<<dim3(22, 16, 2 * E_NUM), 256, 0, stream>>>(wgu, wdn, wgu_t, wd_t);
  router_kernel<<<T_TOK / 4, 256, 0, stream>>>(x, rw, xb, topk_idx, topk_w, meta);
  scan_kernel<<<1, 64, 0, stream>>>(meta, row_token);
  bucket_kernel<<<(2 * T_TOK + 255) / 256, 256, 0, stream>>>(topk_idx, meta, row_token, tok2row);

  // grouped expert MLP
  gemm1_kernel<<<NT1 * MAX_MT, 256, 0, stream>>>(xb, wgu_t, hbuf, row_token, meta);
  gemm2_kernel<<<NT2 * MAX_MT, 256, 0, stream>>>(hbuf, wd_t, part, meta);
  combine_kernel<<<T_TOK, 256, 0, stream>>>(part, tok2row, topk_w, out);
}